// Round 12
// baseline (3718.710 us; speedup 1.0000x reference)
//
#include <hip/hip_runtime.h>
#include <stdint.h>

#define NCAND 100000
#define NB    1024
#define DNUM  96
#define DM    256
#define DH    512
#define MCTX  96
#define LNEPS 1e-5f

typedef __bf16 bf16x8 __attribute__((ext_vector_type(8)));
typedef float  f32x4  __attribute__((ext_vector_type(4)));
typedef unsigned short u16x8 __attribute__((ext_vector_type(8)));
typedef unsigned short us;

__device__ __forceinline__ us f2bf(float x)
{
    unsigned u = __float_as_uint(x);
    unsigned r = u + 0x7FFFu + ((u >> 16) & 1u);   /* RNE */
    return (us)(r >> 16);
}
__device__ __forceinline__ float bfbits(us h)
{
    return __uint_as_float(((unsigned)h) << 16);
}

extern "C" __global__ __launch_bounds__(256)
void split_k(const float* X, us* Xh, us* Xl, long long n)
{
    long long i = (long long)blockIdx.x * 256 + threadIdx.x;
    if (i < n) {
        float x = X[i];
        us h = f2bf(x);
        Xh[i] = h;
        Xl[i] = f2bf(x - bfbits(h));
    }
}

/* pack weight W[Kd,Nd] (f32) into split-bf16 MFMA B-fragment order:
   elem i = ((jt*(Kd/32)+kt)*64+lane)*8+e <-> n=jt*16+(lane&15), k=kt*32+(lane>>4)*8+e */
extern "C" __global__ __launch_bounds__(256)
void packW_k(const float* W, us* Ph, us* Pl, int Kd, int Nd)
{
    int i = blockIdx.x * 256 + threadIdx.x;
    if (i >= Kd * Nd) return;
    int e = i & 7, lane = (i >> 3) & 63, r = i >> 9;
    int KT = Kd >> 5;
    int kt = r % KT, jt = r / KT;
    int n = jt * 16 + (lane & 15);
    int k = kt * 32 + (lane >> 4) * 8 + e;
    float x = W[(long long)k * Nd + n];
    us h = f2bf(x);
    Ph[i] = h;
    Pl[i] = f2bf(x - bfbits(h));
}

/* repack already-split rows R[N,Kd] into B-fragment order */
extern "C" __global__ __launch_bounds__(256)
void packR_k(const us* Rh, const us* Rl, us* Ph, us* Pl, int Kd, int total)
{
    int i = blockIdx.x * 256 + threadIdx.x;
    if (i >= total) return;
    int e = i & 7, lane = (i >> 3) & 63, r = i >> 9;
    int KT = Kd >> 5;
    int kt = r % KT, jt = r / KT;
    int n = jt * 16 + (lane & 15);
    int k = kt * 32 + (lane >> 4) * 8 + e;
    Ph[i] = Rh[(long long)n * Kd + k];
    Pl[i] = Rl[(long long)n * Kd + k];
}

/* repack split rows S[Mr,Kd] (row-major) into MFMA A-fragment order:
   elem i = ((mt*(Kd/32)+kt)*64+lane)*8+e <-> m=mt*16+(lane&15), k=kt*32+(lane>>4)*8+e.
   A wave's A-tile load becomes one contiguous 1KB transaction. Mr%16==0. */
extern "C" __global__ __launch_bounds__(256)
void packA_k(const us* Sh, const us* Sl, us* Ph, us* Pl, int Kd, long long total)
{
    long long i = (long long)blockIdx.x * 256 + threadIdx.x;
    if (i >= total) return;
    int e = (int)(i & 7), lane = (int)((i >> 3) & 63);
    long long r = i >> 9;
    int KT = Kd >> 5;
    int kt = (int)(r % KT);
    long long mt = r / KT;
    long long m = mt * 16 + (lane & 15);
    int k = kt * 32 + (lane >> 4) * 8 + e;
    Ph[i] = Sh[m * Kd + k];
    Pl[i] = Sl[m * Kd + k];
}

/* =====================================================================
   Direct-fragment split-bf16 MFMA GEMM, wave tile M64xN64, block M64xN256,
   grid = (ceil(M/64), N/256). B pre-packed fragment order (1KB/wave tile
   loads, 4 distinct j-tiles per wave). A: row-major split (apk=0) or
   A-fragment-packed (apk=1 -> contiguous 1KB/wave A loads; M%16==0).
   acc = Ah*Bh + Ah*Bl + Al*Bh (f32, rel err ~1e-4).
   Modes: bias/split-resid/relu; f32|split|bf16 out; fused LN via
   cross-wave LDS stats (grid.y==1, N==256); fused row-sumsq; gather-A
   (row = kq[row/96]-kc[gidx[row]] from PACKED kq/kc, hi-only, 2-pass);
   sim transposed write (2*acc - colb[cand], M%16==0). K%32==0.
   ===================================================================== */
extern "C" __global__ __launch_bounds__(256)
void gemm_d(const us* Ah, const us* Al, const us* BPh, const us* BPl,
            float* outF, us* outH, us* outL, us* outB16,
            const float* bias, const us* Rh, const us* Rl, int dorelu,
            const float* lng, const float* lnb, us* lnH, us* lnL,
            float* snOut,
            const us* Gqh, const us* Gql, const us* Gch, const us* Gcl,
            const int* gidx,
            float* simT, const float* colb,
            int M, int N, int K, int apk)
{
    __shared__ float red1[256];
    __shared__ float red2[256];
    __shared__ float mu_s[64];
    __shared__ float rs_s[64];
    int t = threadIdx.x, wave = t >> 6, lane = t & 63;
    int lm = lane & 15, lk = (lane >> 4) * 8, rb = (lane >> 4) * 4;
    int m0b = blockIdx.x * 64;
    int n0 = blockIdx.y * 256;
    int KT = K >> 5;
    int jt0 = (n0 >> 4) + wave * 4;

    f32x4 acc[4][4];
#pragma unroll
    for (int i = 0; i < 4; i++)
#pragma unroll
        for (int j = 0; j < 4; j++)
            for (int e = 0; e < 4; e++) acc[i][j][e] = 0.0f;

    /* gather mode: per-lane packed base offsets (stride 512 elems per kt) */
    long long qb4[4], cb4[4];
    if (gidx) {
#pragma unroll
        for (int i = 0; i < 4; i++) {
            int grow = m0b + i * 16 + lm;
            int gq = 0, gc = 0;
            if (grow < M) { gq = grow / MCTX; gc = gidx[grow]; }
            qb4[i] = (((long long)(gq >> 4) * 8) * 64 + (gq & 15) + (lane >> 4) * 16) * 8;
            cb4[i] = (((long long)(gc >> 4) * 8) * 64 + (gc & 15) + (lane >> 4) * 16) * 8;
        }
    }
    int MT = M >> 4;

    for (int kt = 0; kt < KT; kt++) {
        int k0 = kt * 32;
        bf16x8 fah[4], fal[4];
#pragma unroll
        for (int i = 0; i < 4; i++) {
            u16x8 ah8 = {0,0,0,0,0,0,0,0}, al8 = ah8;
            if (!gidx) {
                if (!apk) {
                    int arow = m0b + i * 16 + lm;
                    if (arow < M) {
                        ah8 = *(const u16x8*)(Ah + (long long)arow * K + k0 + lk);
                        al8 = *(const u16x8*)(Al + (long long)arow * K + k0 + lk);
                    }
                } else {
                    int mt = (m0b >> 4) + i;
                    if (mt < MT) {
                        long long bo = ((long long)mt * KT + kt) * 512 + lane * 8;
                        ah8 = *(const u16x8*)(Ah + bo);
                        al8 = *(const u16x8*)(Al + bo);
                    }
                }
            } else {
                long long qo = qb4[i] + (long long)kt * 512;
                long long co = cb4[i] + (long long)kt * 512;
                u16x8 qh = *(const u16x8*)(Gqh + qo);
                u16x8 ql = *(const u16x8*)(Gql + qo);
                u16x8 ch = *(const u16x8*)(Gch + co);
                u16x8 cl = *(const u16x8*)(Gcl + co);
#pragma unroll
                for (int e = 0; e < 8; e++) {
                    float v = (bfbits(qh[e]) + bfbits(ql[e]))
                            - (bfbits(ch[e]) + bfbits(cl[e]));
                    ah8[e] = f2bf(v);
                }
            }
            fah[i] = *(bf16x8*)&ah8;
            fal[i] = *(bf16x8*)&al8;
        }
#pragma unroll
        for (int j = 0; j < 4; j++) {
            long long bo = ((long long)(jt0 + j) * KT + kt) * 512 + lane * 8;
            u16x8 bu  = *(const u16x8*)(BPh + bo);
            u16x8 blu = *(const u16x8*)(BPl + bo);
            bf16x8 fbh = *(bf16x8*)&bu;
            bf16x8 fbl = *(bf16x8*)&blu;
#pragma unroll
            for (int i = 0; i < 4; i++) {
                acc[i][j] = __builtin_amdgcn_mfma_f32_16x16x32_bf16(fah[i], fbh, acc[i][j], 0, 0, 0);
                acc[i][j] = __builtin_amdgcn_mfma_f32_16x16x32_bf16(fah[i], fbl, acc[i][j], 0, 0, 0);
                if (!gidx)
                    acc[i][j] = __builtin_amdgcn_mfma_f32_16x16x32_bf16(fal[i], fbh, acc[i][j], 0, 0, 0);
            }
        }
    }

    /* C/D layout: col = lane&15 (within j-tile), row = (lane>>4)*4 + e */
    if (simT) {
#pragma unroll
        for (int i = 0; i < 4; i++) {
            int cb = m0b + i * 16;
            if (cb >= M) break;
#pragma unroll
            for (int j = 0; j < 4; j++) {
                int q = n0 + wave * 64 + j * 16 + lm;
                f32x4 v;
                for (int e = 0; e < 4; e++)
                    v[e] = 2.0f * acc[i][j][e] - colb[cb + rb + e];
                *(f32x4*)(simT + (long long)q * NCAND + cb + rb) = v;
            }
        }
        return;
    }

    /* pass 1: bias/resid/relu into acc + primary outputs */
#pragma unroll
    for (int j = 0; j < 4; j++) {
        int col = n0 + wave * 64 + j * 16 + lm;
        float bc = bias ? bias[col] : 0.0f;
#pragma unroll
        for (int i = 0; i < 4; i++) {
            for (int e = 0; e < 4; e++) {
                int row = m0b + i * 16 + rb + e;
                float v = acc[i][j][e] + bc;
                if (row < M) {
                    long long oix = (long long)row * N + col;
                    if (Rh) v += bfbits(Rh[oix]) + bfbits(Rl[oix]);
                    if (dorelu && v < 0.0f) v = 0.0f;
                    if (outF)   outF[oix] = v;
                    if (outB16) outB16[oix] = f2bf(v);
                    if (outH) { us h = f2bf(v); outH[oix] = h; outL[oix] = f2bf(v - bfbits(h)); }
                } else {
                    if (dorelu && v < 0.0f) v = 0.0f;
                }
                acc[i][j][e] = v;
            }
        }
    }

    if (lng || snOut) {
#pragma unroll
        for (int i = 0; i < 4; i++) {
            for (int e = 0; e < 4; e++) {
                int lr = i * 16 + rb + e;
                float s1 = 0.0f, s2 = 0.0f;
#pragma unroll
                for (int j = 0; j < 4; j++) { float v = acc[i][j][e]; s1 += v; s2 += v * v; }
                for (int o = 1; o < 16; o <<= 1) {
                    s1 += __shfl_xor(s1, o, 64);
                    s2 += __shfl_xor(s2, o, 64);
                }
                if (lm == 0) { red1[lr * 4 + wave] = s1; red2[lr * 4 + wave] = s2; }
            }
        }
        __syncthreads();
        if (t < 64) {
            float a = red1[t*4] + red1[t*4+1] + red1[t*4+2] + red1[t*4+3];
            float b2 = red2[t*4] + red2[t*4+1] + red2[t*4+2] + red2[t*4+3];
            if (lng) {
                float mu = a * (1.0f / 256.0f);
                float var = b2 * (1.0f / 256.0f) - mu * mu;
                mu_s[t] = mu;
                rs_s[t] = rsqrtf(var + LNEPS);
            }
            if (snOut && (m0b + t) < M) snOut[m0b + t] = b2;
        }
        __syncthreads();
        if (lng) {
#pragma unroll
            for (int j = 0; j < 4; j++) {
                int col = n0 + wave * 64 + j * 16 + lm;
                float g = lng[col], bb = lnb[col];
#pragma unroll
                for (int i = 0; i < 4; i++) {
                    for (int e = 0; e < 4; e++) {
                        int lr = i * 16 + rb + e;
                        int row = m0b + lr;
                        if (row >= M) continue;
                        float y = (acc[i][j][e] - mu_s[lr]) * rs_s[lr] * g + bb;
                        long long oix = (long long)row * N + col;
                        us h = f2bf(y);
                        lnH[oix] = h;
                        lnL[oix] = f2bf(y - bfbits(h));
                    }
                }
            }
        }
    }
}

__device__ unsigned fmapf(float f)
{
    unsigned u = __float_as_uint(f);
    return u ^ (unsigned)(((int)u >> 31) | (int)0x80000000);
}

/* exact top-96 (radix select 4x8-bit, ties -> smallest index) + softmax */
extern "C" __global__ __launch_bounds__(1024)
void topk_k(const float* S, int q0, int* out_idx, float* out_p)
{
    int t = threadIdx.x;
    const float* row = S + (long long)blockIdx.x * NCAND;
    const float4* row4 = (const float4*)row;
    __shared__ int hist8[8][256];
    __shared__ unsigned sh_prefix;
    __shared__ int sh_want, cntG, cntE;
    __shared__ int   gidx[128];
    __shared__ float gval[128];
    __shared__ int   eqi[2048];
    __shared__ float vals[MCTX];
    __shared__ int   inds[MCTX];
    __shared__ float pr[MCTX];

    if (t == 0) { sh_prefix = 0u; sh_want = MCTX; cntG = 0; cntE = 0; }

    for (int lvl = 0; lvl < 4; lvl++) {
        int shift = 24 - 8 * lvl;
        for (int i = t; i < 2048; i += 1024) ((int*)hist8)[i] = 0;
        __syncthreads();
        unsigned prefix = sh_prefix;
        unsigned mask = (lvl == 0) ? 0u : (0xFFFFFFFFu << (shift + 8));
        int* hrow = hist8[t & 7];
        for (int c = t; c < NCAND / 4; c += 1024) {
            float4 v = row4[c];
            unsigned k0 = fmapf(v.x), k1 = fmapf(v.y), k2 = fmapf(v.z), k3 = fmapf(v.w);
            if ((k0 & mask) == prefix) atomicAdd(&hrow[(k0 >> shift) & 255], 1);
            if ((k1 & mask) == prefix) atomicAdd(&hrow[(k1 >> shift) & 255], 1);
            if ((k2 & mask) == prefix) atomicAdd(&hrow[(k2 >> shift) & 255], 1);
            if ((k3 & mask) == prefix) atomicAdd(&hrow[(k3 >> shift) & 255], 1);
        }
        __syncthreads();
        if (t < 256) {
            int s = 0;
            for (int g2 = 1; g2 < 8; g2++) s += hist8[g2][t];
            hist8[0][t] += s;
        }
        __syncthreads();
        if (t == 0) {
            int want = sh_want, cum = 0;
            for (int b2 = 255; b2 >= 0; b2--) {
                cum += hist8[0][b2];
                if (cum >= want) {
                    sh_want = want - (cum - hist8[0][b2]);
                    sh_prefix = prefix | ((unsigned)b2 << shift);
                    break;
                }
            }
        }
        __syncthreads();
    }
    unsigned T = sh_prefix;
    for (int c = t; c < NCAND / 4; c += 1024) {
        float4 v = row4[c];
        float vv[4]; vv[0] = v.x; vv[1] = v.y; vv[2] = v.z; vv[3] = v.w;
        for (int e = 0; e < 4; e++) {
            unsigned key = fmapf(vv[e]);
            if (key > T) {
                int p = atomicAdd(&cntG, 1);
                if (p < 128) { gidx[p] = c * 4 + e; gval[p] = vv[e]; }
            } else if (key == T) {
                int p = atomicAdd(&cntE, 1);
                if (p < 2048) eqi[p] = c * 4 + e;
            }
        }
    }
    __syncthreads();
    if (t == 0) {
        int nG = cntG; if (nG > MCTX) nG = MCTX;
        int nE = cntE; if (nE > 2048) nE = 2048;
        int need = MCTX - nG;
        for (int i = 0; i < nG; i++) { inds[i] = gidx[i]; vals[i] = gval[i]; }
        for (int s = 0; s < need; s++) {
            int best = 0x7FFFFFFF, bp = -1;
            for (int e = 0; e < nE; e++) if (eqi[e] < best) { best = eqi[e]; bp = e; }
            if (bp >= 0) { eqi[bp] = 0x7FFFFFFF; inds[nG + s] = best; vals[nG + s] = row[best]; }
            else         { inds[nG + s] = 0;     vals[nG + s] = -3.0e38f; }
        }
        float mx = -3.4e38f;
        for (int i = 0; i < MCTX; i++) if (vals[i] > mx) mx = vals[i];
        float sum = 0.0f;
        for (int i = 0; i < MCTX; i++) { float e = expf(vals[i] - mx); pr[i] = e; sum += e; }
        float inv = 1.0f / sum;
        for (int i = 0; i < MCTX; i++) pr[i] *= inv;
    }
    __syncthreads();
    if (t < MCTX) {
        long long o = (long long)(q0 + blockIdx.x) * MCTX + t;
        out_idx[o] = inds[t];
        out_p[o]   = pr[t];
    }
}

extern "C" __global__ __launch_bounds__(256)
void ybar_k(const float* P, const int* idx, const float* y, float* ybar)
{
    __shared__ float sred[256];
    int b = blockIdx.x, t = threadIdx.x;
    float v = 0.0f;
    if (t < MCTX) v = P[(long long)b * MCTX + t] * y[idx[(long long)b * MCTX + t]];
    sred[t] = v; __syncthreads();
    for (int s = 128; s > 0; s >>= 1) { if (t < s) sred[t] += sred[t + s]; __syncthreads(); }
    if (t == 0) ybar[b] = sred[0];
}

/* tier A: u[b,j] = sum_m p_m * relu(Pq[b,j] - R[idx_m, j]) */
extern "C" __global__ __launch_bounds__(512)
void wsum2_k(const float* Pq, const float* R, const float* P, const int* idx, float* u)
{
    __shared__ float pl[MCTX];
    __shared__ int ix[MCTX];
    int b = blockIdx.x, j = threadIdx.x;
    if (j < MCTX) {
        pl[j] = P[(long long)b * MCTX + j];
        ix[j] = idx[(long long)b * MCTX + j];
    }
    __syncthreads();
    float pb = Pq[(long long)b * DH + j];
    float a = 0.0f;
    for (int m = 0; m < MCTX; m++) {
        float d = pb - R[(long long)ix[m] * DH + j];
        a += pl[m] * (d > 0.0f ? d : 0.0f);
    }
    u[(long long)b * DH + j] = a;
}

/* tier B: u[b,j] = sum_m p_m * U[(b,m),j], U plain bf16 */
extern "C" __global__ __launch_bounds__(512)
void wsum_k(const us* U, const float* P, float* u)
{
    __shared__ float pl[MCTX];
    int b = blockIdx.x, j = threadIdx.x;
    if (j < MCTX) pl[j] = P[(long long)b * MCTX + j];
    __syncthreads();
    const us* Ub = U + (long long)b * MCTX * DH;
    float acc = 0.0f;
    for (int m = 0; m < MCTX; m++) acc += pl[m] * bfbits(Ub[(long long)m * DH + j]);
    u[(long long)b * DH + j] = acc;
}

extern "C" __global__ __launch_bounds__(256)
void mixprep_sp(us* h2h, us* h2l, const float* ybar,
                const float* Wy, const float* by, const float* bt2)
{
    int b = blockIdx.x, d = threadIdx.x;
    long long i = (long long)b * DM + d;
    float v = bfbits(h2h[i]) + bfbits(h2l[i]) + ybar[b] * Wy[d] + by[d] + bt2[d];
    us h = f2bf(v);
    h2h[i] = h;
    h2l[i] = f2bf(v - bfbits(h));
}

extern "C" __global__ __launch_bounds__(256)
void head_k(const float* X, const float* g, const float* bln, const float* Wh,
            const float* bh, float* out)
{
    __shared__ float sred[256];
    int r = blockIdx.x, t = threadIdx.x;
    float x = X[(long long)r * DM + t];
    sred[t] = x; __syncthreads();
    for (int s = 128; s > 0; s >>= 1) { if (t < s) sred[t] += sred[t + s]; __syncthreads(); }
    float mu = sred[0] * (1.0f / DM); __syncthreads();
    float d = x - mu;
    sred[t] = d * d; __syncthreads();
    for (int s = 128; s > 0; s >>= 1) { if (t < s) sred[t] += sred[t + s]; __syncthreads(); }
    float var = sred[0] * (1.0f / DM); __syncthreads();
    float ln = d * rsqrtf(var + LNEPS) * g[t] + bln[t];
    float rl = (ln > 0.0f) ? ln : 0.0f;
    sred[t] = rl * Wh[t]; __syncthreads();
    for (int s = 128; s > 0; s >>= 1) { if (t < s) sred[t] += sred[t + s]; __syncthreads(); }
    if (t == 0) out[r] = sred[0] + bh[0];
}

#define ZU (us*)0
#define ZCU (const us*)0
#define ZF (float*)0
#define ZCF (const float*)0
#define ZI (const int*)0

extern "C" void kernel_launch(void* const* d_in, const int* in_sizes, int n_in,
                              void* d_out, int out_size, void* d_ws, size_t ws_size,
                              hipStream_t stream)
{
    const float* x_num  = (const float*)d_in[0];
    const float* cand_x = (const float*)d_in[1];
    const float* cand_y = (const float*)d_in[2];
    const float* W_in = (const float*)d_in[4];
    const float* b_in = (const float*)d_in[5];
    const float* We1  = (const float*)d_in[6];
    const float* be1  = (const float*)d_in[7];
    const float* We2  = (const float*)d_in[8];
    const float* be2  = (const float*)d_in[9];
    const float* g_m  = (const float*)d_in[10];
    const float* b_m  = (const float*)d_in[11];
    const float* Ws   = (const float*)d_in[12];
    const float* bs   = (const float*)d_in[13];
    const float* Wy   = (const float*)d_in[14];
    const float* by   = (const float*)d_in[15];
    const float* Wt1  = (const float*)d_in[16];
    const float* Wt2  = (const float*)d_in[17];
    const float* bt2  = (const float*)d_in[18];
    const float* Wp1  = (const float*)d_in[19];
    const float* bp1  = (const float*)d_in[20];
    const float* Wp2  = (const float*)d_in[21];
    const float* bp2  = (const float*)d_in[22];
    const float* g_h  = (const float*)d_in[23];
    const float* b_h  = (const float*)d_in[24];
    const float* Wh   = (const float*)d_in[25];
    const float* bh   = (const float*)d_in[26];
    float* out = (float*)d_out;

    char* p = (char*)d_ws;
    us* WinPh = (us*)p; p += 256*96*2;   us* WinPl = (us*)p; p += 256*96*2;
    us* We1Ph = (us*)p; p += 512*256*2;  us* We1Pl = (us*)p; p += 512*256*2;
    us* We2Ph = (us*)p; p += 256*512*2;  us* We2Pl = (us*)p; p += 256*512*2;
    us* WsPh  = (us*)p; p += 256*256*2;  us* WsPl  = (us*)p; p += 256*256*2;
    us* Wt1Ph = (us*)p; p += 512*256*2;  us* Wt1Pl = (us*)p; p += 512*256*2;
    us* Wt2Ph = (us*)p; p += 256*512*2;  us* Wt2Pl = (us*)p; p += 256*512*2;
    us* Wp1Ph = (us*)p; p += 512*256*2;  us* Wp1Pl = (us*)p; p += 512*256*2;
    us* Wp2Ph = (us*)p; p += 256*512*2;  us* Wp2Pl = (us*)p; p += 256*512*2;
    us* XNh  = (us*)p; p += (long long)NB*DNUM*2;  us* XNl  = (us*)p; p += (long long)NB*DNUM*2;
    us* HQ1h = (us*)p; p += (long long)NB*DM*2;    us* HQ1l = (us*)p; p += (long long)NB*DM*2;
    us* TQh  = (us*)p; p += (long long)NB*DH*2;    us* TQl  = (us*)p; p += (long long)NB*DH*2;
    us* HQ2h = (us*)p; p += (long long)NB*DM*2;    us* HQ2l = (us*)p; p += (long long)NB*DM*2;
    us* LNQh = (us*)p; p += (long long)NB*DM*2;    us* LNQl = (us*)p; p += (long long)NB*DM*2;
    us* KQh  = (us*)p; p += (long long)NB*DM*2;    us* KQl  = (us*)p; p += (long long)NB*DM*2;
    us* KQPh = (us*)p; p += (long long)NB*DM*2;    us* KQPl = (us*)p; p += (long long)NB*DM*2;
    us* KQAh = (us*)p; p += (long long)NB*DM*2;    us* KQAl = (us*)p; p += (long long)NB*DM*2;
    us* XQh  = (us*)p; p += (long long)NB*DM*2;    us* XQl  = (us*)p; p += (long long)NB*DM*2;
    us* UQvh = (us*)p; p += (long long)NB*DH*2;    us* UQvl = (us*)p; p += (long long)NB*DH*2;
    float* UQv  = (float*)p; p += (long long)NB*DH*4;
    float* Pq   = (float*)p; p += (long long)NB*DH*4;
    float* XQ2f = (float*)p; p += (long long)NB*DM*4;
    float* YB   = (float*)p; p += (long long)NB*4;
    int*   IDX  = (int*)p;   p += (long long)NB*MCTX*4;
    float* PRB  = (float*)p; p += (long long)NB*MCTX*4;
    us* KCAh = (us*)p; p += (long long)NCAND*DM*2;  us* KCAl = (us*)p; p += (long long)NCAND*DM*2;
    float* SC = (float*)p; p += (long long)NCAND*4;

    size_t used = (size_t)(p - (char*)d_ws);
    long long avail = (ws_size > used + 4096) ? (long long)(ws_size - used - 4096) : 0;
    /* encode chunk needs CX(38.4MB) + EC*5120 B (Hc/Tc/LNc/KCr splits); EC%16==0 */
    int EC = 6400;
    if      (avail >= 301000000LL) EC = 51200;
    else if (avail >= 170000000LL) EC = 25600;
    else if (avail >= 104500000LL) EC = 12800;
    int QS = (avail >= 204800000LL) ? 512 : 256;
    int tierA = (avail >= 204800000LL) ? 1 : 0;
    int VC = (avail >= 100700000LL) ? 1024 : 512;

    char* AR = p;
    us* CXh = (us*)AR;
    us* CXl = CXh + (long long)NCAND*DNUM;
    char* EB = AR + (long long)NCAND*DNUM*4;
    us* Hch  = (us*)EB;                               us* Hcl  = Hch + (long long)EC*DM;
    us* Tch  = (us*)(EB + (long long)EC*DM*4);        us* Tcl  = Tch + (long long)EC*DH;
    us* LNch = (us*)(EB + (long long)EC*(DM+DH)*4);   us* LNcl = LNch + (long long)EC*DM;
    us* KCrh = (us*)(EB + (long long)EC*(2*DM+DH)*4); us* KCrl = KCrh + (long long)EC*DM;
    float* Sb = (float*)AR;
    float* R  = (float*)AR;
    us* Ub = (us*)AR;

    dim3 blk(256);

    /* ---- one-time weight packs + activation splits ---- */
    packW_k<<<dim3((DNUM*DM+255)/256), blk, 0, stream>>>(W_in, WinPh, WinPl, DNUM, DM);
    packW_k<<<dim3((DM*DH+255)/256), blk, 0, stream>>>(We1, We1Ph, We1Pl, DM, DH);
    packW_k<<<dim3((DH*DM+255)/256), blk, 0, stream>>>(We2, We2Ph, We2Pl, DH, DM);
    packW_k<<<dim3((DM*DM+255)/256), blk, 0, stream>>>(Ws,  WsPh,  WsPl,  DM, DM);
    packW_k<<<dim3((DM*DH+255)/256), blk, 0, stream>>>(Wt1, Wt1Ph, Wt1Pl, DM, DH);
    packW_k<<<dim3((DH*DM+255)/256), blk, 0, stream>>>(Wt2, Wt2Ph, Wt2Pl, DH, DM);
    packW_k<<<dim3((DM*DH+255)/256), blk, 0, stream>>>(Wp1, Wp1Ph, Wp1Pl, DM, DH);
    packW_k<<<dim3((DH*DM+255)/256), blk, 0, stream>>>(Wp2, Wp2Ph, Wp2Pl, DH, DM);
    split_k<<<dim3((NB*DNUM+255)/256), blk, 0, stream>>>(x_num, XNh, XNl, (long long)NB*DNUM);
    split_k<<<dim3((NCAND*DNUM+255)/256), blk, 0, stream>>>(cand_x, CXh, CXl, (long long)NCAND*DNUM);

    /* ---- query encode ---- */
    gemm_d<<<dim3(NB/64, 1), blk, 0, stream>>>(XNh, XNl, WinPh, WinPl,
        ZF, HQ1h, HQ1l, ZU, b_in, ZCU, ZCU, 0, ZCF, ZCF, ZU, ZU, ZF,
        ZCU, ZCU, ZCU, ZCU, ZI, ZF, ZCF, NB, DM, DNUM, 0);
    gemm_d<<<dim3(NB/64, 2), blk, 0, stream>>>(HQ1h, HQ1l, We1Ph, We1Pl,
        ZF, TQh, TQl, ZU, be1, ZCU, ZCU, 1, ZCF, ZCF, ZU, ZU, ZF,
        ZCU, ZCU, ZCU, ZCU, ZI, ZF, ZCF, NB, DH, DM, 0);
    gemm_d<<<dim3(NB/64, 1), blk, 0, stream>>>(TQh, TQl, We2Ph, We2Pl,
        ZF, HQ2h, HQ2l, ZU, be2, HQ1h, HQ1l, 0, g_m, b_m, LNQh, LNQl, ZF,
        ZCU, ZCU, ZCU, ZCU, ZI, ZF, ZCF, NB, DM, DH, 0);
    gemm_d<<<dim3(NB/64, 1), blk, 0, stream>>>(LNQh, LNQl, WsPh, WsPl,
        ZF, KQh, KQl, ZU, bs, ZCU, ZCU, 0, ZCF, ZCF, ZU, ZU, ZF,
        ZCU, ZCU, ZCU, ZCU, ZI, ZF, ZCF, NB, DM, DM, 0);
    packR_k<<<dim3((NB*DM+255)/256), blk, 0, stream>>>(KQh, KQl, KQPh, KQPl, DM, NB*DM);
    packA_k<<<dim3((NB*DM+255)/256), blk, 0, stream>>>(KQh, KQl, KQAh, KQAl, DM, (long long)NB*DM);

    /* ---- candidate encode (fused LN, fused ||k||^2, A-packed KC) ---- */
    for (int c0 = 0; c0 < NCAND; c0 += EC) {
        int Mc = (NCAND - c0 < EC) ? (NCAND - c0) : EC;
        int gx = (Mc + 63) / 64;
        gemm_d<<<dim3(gx, 1), blk, 0, stream>>>(CXh + (long long)c0*DNUM, CXl + (long long)c0*DNUM,
            WinPh, WinPl, ZF, Hch, Hcl, ZU, b_in, ZCU, ZCU, 0, ZCF, ZCF, ZU, ZU, ZF,
            ZCU, ZCU, ZCU, ZCU, ZI, ZF, ZCF, Mc, DM, DNUM, 0);
        gemm_d<<<dim3(gx, 2), blk, 0, stream>>>(Hch, Hcl, We1Ph, We1Pl,
            ZF, Tch, Tcl, ZU, be1, ZCU, ZCU, 1, ZCF, ZCF, ZU, ZU, ZF,
            ZCU, ZCU, ZCU, ZCU, ZI, ZF, ZCF, Mc, DH, DM, 0);
        gemm_d<<<dim3(gx, 1), blk, 0, stream>>>(Tch, Tcl, We2Ph, We2Pl,
            ZF, ZU, ZU, ZU, be2, Hch, Hcl, 0, g_m, b_m, LNch, LNcl, ZF,
            ZCU, ZCU, ZCU, ZCU, ZI, ZF, ZCF, Mc, DM, DH, 0);
        gemm_d<<<dim3(gx, 1), blk, 0, stream>>>(LNch, LNcl, WsPh, WsPl,
            ZF, KCrh, KCrl, ZU, bs, ZCU, ZCU, 0,
            ZCF, ZCF, ZU, ZU, SC + c0,
            ZCU, ZCU, ZCU, ZCU, ZI, ZF, ZCF, Mc, DM, DM, 0);
        packA_k<<<dim3((int)(((long long)Mc*DM + 255) / 256)), blk, 0, stream>>>(
            KCrh, KCrl, KCAh + (long long)c0*DM, KCAl + (long long)c0*DM, DM, (long long)Mc*DM);
    }

    /* ---- sim (2*k.ck - ||ck||^2, transposed write; A=packed KC) + top-96 ---- */
    for (int q0 = 0; q0 < NB; q0 += QS) {
        gemm_d<<<dim3((NCAND + 63) / 64, QS / 256), blk, 0, stream>>>(KCAh, KCAl,
            KQPh + (long long)q0*DM, KQPl + (long long)q0*DM,
            ZF, ZU, ZU, ZU, ZCF, ZCU, ZCU, 0, ZCF, ZCF, ZU, ZU, ZF,
            ZCU, ZCU, ZCU, ZCU, ZI, Sb, SC, NCAND, QS, DM, 1);
        topk_k<<<dim3(QS), dim3(1024), 0, stream>>>(Sb, q0, IDX, PRB);
    }

    /* ---- value aggregation ---- */
    ybar_k<<<dim3(NB), blk, 0, stream>>>(PRB, IDX, cand_y, YB);
    gemm_d<<<dim3(NB/64, 2), blk, 0, stream>>>(KQAh, KQAl, Wt1Ph, Wt1Pl,
        Pq, ZU, ZU, ZU, ZCF, ZCU, ZCU, 0, ZCF, ZCF, ZU, ZU, ZF,
        ZCU, ZCU, ZCU, ZCU, ZI, ZF, ZCF, NB, DH, DM, 1);
    if (tierA) {
        gemm_d<<<dim3((NCAND + 63) / 64, 2), blk, 0, stream>>>(KCAh, KCAl, Wt1Ph, Wt1Pl,
            R, ZU, ZU, ZU, ZCF, ZCU, ZCU, 0, ZCF, ZCF, ZU, ZU, ZF,
            ZCU, ZCU, ZCU, ZCU, ZI, ZF, ZCF, NCAND, DH, DM, 1);
        wsum2_k<<<dim3(NB), dim3(512), 0, stream>>>(Pq, R, PRB, IDX, UQv);
    } else {
        for (int v0 = 0; v0 < NB; v0 += VC) {
            gemm_d<<<dim3((VC * MCTX) / 64, 2), blk, 0, stream>>>(ZCU, ZCU, Wt1Ph, Wt1Pl,
                ZF, ZU, ZU, Ub, ZCF, ZCU, ZCU, 1, ZCF, ZCF, ZU, ZU, ZF,
                KQAh + (long long)((v0/MCTX>0)?0:0), KQAl, KCAh, KCAl,
                IDX + (long long)v0*MCTX, ZF, ZCF, VC * MCTX, DH, DM, 0);
            /* NOTE: gather rows are grow=v0*MCTX-relative; pass global query
               base by offsetting gidx only — query index = grow/MCTX must be
               global, so launch with full-row indexing: */
            wsum_k<<<dim3(VC), dim3(512), 0, stream>>>(Ub, PRB + (long long)v0*MCTX,
                                                       UQv + (long long)v0*DH);
        }
    }
    split_k<<<dim3((NB*DH+255)/256), blk, 0, stream>>>(UQv, UQvh, UQvl, (long long)NB*DH);
    mixprep_sp<<<dim3(NB), blk, 0, stream>>>(HQ2h, HQ2l, YB, Wy, by, bt2);
    gemm_d<<<dim3(NB/64, 1), blk, 0, stream>>>(UQvh, UQvl, Wt2Ph, Wt2Pl,
        ZF, XQh, XQl, ZU, ZCF, HQ2h, HQ2l, 0, ZCF, ZCF, ZU, ZU, ZF,
        ZCU, ZCU, ZCU, ZCU, ZI, ZF, ZCF, NB, DM, DH, 0);

    /* ---- predictor block + head ---- */
    gemm_d<<<dim3(NB/64, 2), blk, 0, stream>>>(XQh, XQl, Wp1Ph, Wp1Pl,
        ZF, TQh, TQl, ZU, bp1, ZCU, ZCU, 1, ZCF, ZCF, ZU, ZU, ZF,
        ZCU, ZCU, ZCU, ZCU, ZI, ZF, ZCF, NB, DH, DM, 0);
    gemm_d<<<dim3(NB/64, 1), blk, 0, stream>>>(TQh, TQl, Wp2Ph, Wp2Pl,
        XQ2f, ZU, ZU, ZU, bp2, XQh, XQl, 0, ZCF, ZCF, ZU, ZU, ZF,
        ZCU, ZCU, ZCU, ZCU, ZI, ZF, ZCF, NB, DM, DH, 0);
    head_k<<<dim3(NB), blk, 0, stream>>>(XQ2f, g_h, b_h, Wh, bh, out);
}